// Round 9
// baseline (2485.668 us; speedup 1.0000x reference)
//
#include <hip/hip_runtime.h>

// ReservoirLayer: S0 = pad(x,[2048,4096]); 16x: S = leaky_relu(S @ W, 0.1)
// fp32-emulation via fp16 hi/lo split (fp16x3): acc = Sh@Wh + Sl@Wh + Sh@Wl.
// R3 base: depth-2 pipeline, 16x16x32 MFMA, XOR-chunk LDS layout (0 conflicts).
// R10: counted-vmcnt raw barriers (neutral -> drain wasn't the stall).
// R11: (a) B DIRECT FROM GLOBAL in a tiled W' format (prep_w builds
//     [nb16][kt][lane][8]: one wave B-frag = one coalesced 1KB dwordx4 burst).
//     LDS now holds only A -> LDS pipe ~1024 cyc << MFMA ~1978 cyc, off the
//     critical path. B(t) loads issue at top of half t, consumed half t+1
//     (~800 cyc cover); counted vmcnt(12) waits never touch them (R9's
//     failure was __syncthreads vmcnt(0) draining B every half-iter).
//     (b) term-major MFMAS: same-acc reuse distance 16 instrs (was 1) --
//     kills accumulate-latency bubbles. Per-acc term order unchanged ->
//     bit-identical numerics.
// R12 == R11 resubmission: round-8 failure was harness-level (container
//     failed before pytest; no timing/pass data). Kernel re-audited: uniform
//     barriers, vmcnt counts can under-wait but not deadlock, prep_w
//     bijective. No code change.

#define BATCH 2048
#define NDIM  4096
#define INDIM 512
#define BM 128
#define BN 128
#define BK 32

typedef _Float16 f16x4 __attribute__((ext_vector_type(4)));
typedef _Float16 f16x8 __attribute__((ext_vector_type(8)));
typedef float    f32x4 __attribute__((ext_vector_type(4)));

__device__ __forceinline__ void async16(const void* gsrc, void* ldst) {
  const __attribute__((address_space(1))) unsigned int* g =
      (const __attribute__((address_space(1))) unsigned int*)gsrc;
  __attribute__((address_space(3))) unsigned int* l =
      (__attribute__((address_space(3))) unsigned int*)ldst;
  __builtin_amdgcn_global_load_lds(g, l, 16, 0, 0);
}

#define WAITV12() do { asm volatile("s_waitcnt vmcnt(12)" ::: "memory"); \
                       __builtin_amdgcn_sched_barrier(0); } while (0)
#define WAITV8()  do { asm volatile("s_waitcnt vmcnt(8)" ::: "memory");  \
                       __builtin_amdgcn_sched_barrier(0); } while (0)
#define LGKM0()   do { asm volatile("s_waitcnt lgkmcnt(0)" ::: "memory"); \
                       __builtin_amdgcn_sched_barrier(0); } while (0)
#define SBAR()    __builtin_amdgcn_s_barrier()

// ---------------- prep: split+pad x into S_hi/S_lo ----------------
__global__ void prep_x(const float* __restrict__ x,
                       _Float16* __restrict__ Sh, _Float16* __restrict__ Sl) {
  size_t i = (size_t)blockIdx.x * 256 + threadIdx.x;  // over BATCH*NDIM
  int b = (int)(i >> 12);
  int n = (int)(i & (NDIM - 1));
  float v = (n < INDIM) ? x[(size_t)b * INDIM + n] : 0.0f;
  _Float16 h = (_Float16)v;
  Sh[i] = h;
  Sl[i] = (_Float16)(v - (float)h);
}

// -- prep: transpose + scale(256) + split W into frag-tiled W' format --
// W'[nb][kt][L][e] (nb = n>>4, kt = k>>5, L = fq*16+fm, e = k&7):
//   holds Wt[n = nb*16+fm][k = kt*32 + fq*8 + e] * 256
// so a wave's B-frag (col-block nb, tile kt) is the contiguous 1KB span
// base + lane*16B -- one global_load_dwordx4 per lane, perfectly coalesced.
__global__ void prep_w(const float* __restrict__ W,
                       _Float16* __restrict__ Wth, _Float16* __restrict__ Wtl) {
  __shared__ float tile[32][33];
  int nb2 = blockIdx.x, ktb = blockIdx.y;
  int k0 = ktb * 32, n0 = nb2 * 32;
  int tx = threadIdx.x, ty = threadIdx.y;  // 32 x 8
  for (int r = 0; r < 4; r++) {
    int kl = ty + r * 8;
    tile[kl][tx] = W[(size_t)(k0 + kl) * NDIM + n0 + tx];  // tile[k][n]
  }
  __syncthreads();
  int tid = ty * 32 + tx;
  int r2 = tid >> 7;            // which 16-col half of the 32-col tile
  int t128 = tid & 127;
  int L = t128 >> 1;            // lane 0..63
  int e0 = (t128 & 1) * 4;      // first of 4 k-elems
  int fq = L >> 4, fm = L & 15;
  int nl = r2 * 16 + fm;
  f16x4 hi4, lo4;
#pragma unroll
  for (int q = 0; q < 4; q++) {
    float v = tile[fq * 8 + e0 + q][nl] * 256.0f;
    _Float16 h = (_Float16)v;
    hi4[q] = h;
    lo4[q] = (_Float16)(v - (float)h);
  }
  size_t base = (((size_t)(nb2 * 2 + r2) * 128 + ktb) << 9) + L * 8 + e0;
  *(f16x4*)&Wth[base] = hi4;
  *(f16x4*)&Wtl[base] = lo4;
}

// A frags from LDS buffer b (compile-time 0/1 at all call sites)
#define READFA(b, A, L)                                \
  do {                                                 \
    _Pragma("unroll") for (int i = 0; i < 4; i++) {    \
      A[i] = *(const f16x8*)&sAh[b][oA[i]];            \
      L[i] = *(const f16x8*)&sAl[b][oA[i]];            \
    }                                                  \
  } while (0)

// B frags direct from global W' at tile kt (1KB coalesced per load)
#define LOADB(Bv, M, kt)                               \
  do {                                                 \
    _Pragma("unroll") for (int j = 0; j < 4; j++) {    \
      size_t g = gB[j] + ((size_t)(kt) << 9);          \
      Bv[j] = *(const f16x8*)&Bh[g];                   \
      M[j]  = *(const f16x8*)&Bl[g];                   \
    }                                                  \
  } while (0)

// term-major: same-acc reuse distance = 16 instructions; per-acc term order
// stays AB -> LB -> AM (bit-identical to the previous interleaved form).
#define MFMAS(A, L, Bv, M)                                                          \
  do {                                                                              \
    _Pragma("unroll") for (int j = 0; j < 4; j++)                                   \
    _Pragma("unroll") for (int i = 0; i < 4; i++)                                   \
      acc[i][j] = __builtin_amdgcn_mfma_f32_16x16x32_f16(A[i], Bv[j], acc[i][j], 0, 0, 0); \
    _Pragma("unroll") for (int j = 0; j < 4; j++)                                   \
    _Pragma("unroll") for (int i = 0; i < 4; i++)                                   \
      acc[i][j] = __builtin_amdgcn_mfma_f32_16x16x32_f16(L[i], Bv[j], acc[i][j], 0, 0, 0); \
    _Pragma("unroll") for (int j = 0; j < 4; j++)                                   \
    _Pragma("unroll") for (int i = 0; i < 4; i++)                                   \
      acc[i][j] = __builtin_amdgcn_mfma_f32_16x16x32_f16(A[i], M[j], acc[i][j], 0, 0, 0); \
  } while (0)

// ---------------- one recurrence step ----------------
template <int MODE>
__global__ __launch_bounds__(256, 2) void step_kernel(
    const _Float16* __restrict__ Ah, const _Float16* __restrict__ Al,
    const _Float16* __restrict__ Bh, const _Float16* __restrict__ Bl,
    _Float16* __restrict__ Dh, _Float16* __restrict__ Dl,
    float* __restrict__ Dout, int k_len) {
  __shared__ _Float16 sAh[2][BM * BK];   // A only: 16 KB
  __shared__ _Float16 sAl[2][BM * BK];   // 16 KB

  const int tid = threadIdx.x;
  const int lane = tid & 63;
  const int w = tid >> 6;
  const int wm = w >> 1, wn = w & 1;

  // XCD-aware swizzle: 8x8 block region per XCD (round-robin dispatch, id&7)
  int id = blockIdx.x;
  int xcd = id & 7, local = id >> 3;
  int lr = local & 7, lc = local >> 3;
  const int bm = ((xcd & 1) * 8 + lr) * BM;
  const int bn = ((xcd >> 1) * 8 + lc) * BN;

  const int sr = lane >> 2, cl = lane & 3;
  const int fm = lane & 15, fq = lane >> 4;

  // loop-invariant LDS A-fragment element-offsets (k-chunk swizzled)
  int oA[4];
#pragma unroll
  for (int i = 0; i < 4; i++) {
    int rA = wm * 64 + i * 16 + fm;
    oA[i] = rA * BK + (fq ^ ((rA >> 1) & 3)) * 8;
  }

  // loop-invariant B global bases: col-block nbB, element (lane*8)
  size_t gB[4];
#pragma unroll
  for (int j = 0; j < 4; j++) {
    int nbB = (bn >> 4) + wn * 4 + j;
    gB[j] = ((size_t)nbB << 16) + lane * 8;
  }

  // A staging addresses (k element-offset added per call): 4 async16/wave
  int r0 = w * 32 + sr, r1 = r0 + 16;
  int cg0 = cl ^ ((r0 >> 1) & 3);
  int cg1 = cl ^ ((r1 >> 1) & 3);
  const size_t gA0 = (size_t)(bm + r0) * NDIM + cg0 * 8;
  const size_t gA1 = (size_t)(bm + r1) * NDIM + cg1 * 8;
  const int lo0 = r0 * BK + cl * 8;
  const int lo1 = r1 * BK + cl * 8;

  auto stage = [&](int kt, int b) {   // 4 global_load_lds per wave
    async16(Ah + gA0 + kt, &sAh[b][lo0]);
    async16(Ah + gA1 + kt, &sAh[b][lo1]);
    async16(Al + gA0 + kt, &sAl[b][lo0]);
    async16(Al + gA1 + kt, &sAl[b][lo1]);
  };

  f32x4 acc[4][4];
#pragma unroll
  for (int i = 0; i < 4; i++)
#pragma unroll
    for (int j = 0; j < 4; j++) acc[i][j] = (f32x4){0.f, 0.f, 0.f, 0.f};

  f16x8 a0[4], l0[4], b0[4], m0[4];  // set 0 (even tiles)
  f16x8 a1[4], l1[4], b1[4], m1[4];  // set 1 (odd tiles)

  const int nk = k_len / BK;  // 16 or 128 (even)

  // prologue
  stage(0 * BK, 0);            // 4 vm
  stage(1 * BK, 1);            // 4 vm
  LOADB(b0, m0, 0);            // 8 vm (B tile 0)
  WAITV12(); SBAR();           // stage(0) done (allowed: s1 + B0 = 12)
  READFA(0, a0, l0);
  LGKM0(); SBAR();             // buf0 reads retired chip-wide
  stage(2 * BK, 0);            // 4 vm

  // half(it): WAITV12|SBAR -> LOADB(it) + READFA(it) -> MFMAS(it-1)
  //           -> LGKM0|SBAR -> stage(it+2)
  int it = 1;
  for (; it + 1 < nk; it += 2) {
    WAITV12(); SBAR();               // stage(it) done
    LOADB(b1, m1, it);               // B(it), consumed next half
    READFA(1, a1, l1);               // A(it)
    MFMAS(a0, l0, b0, m0);           // tile it-1 (compiler waits B(it-1))
    LGKM0(); SBAR();
    if (it + 2 < nk) stage((it + 2) * BK, 1);

    WAITV12(); SBAR();               // stage(it+1) done
    LOADB(b0, m0, it + 1);
    READFA(0, a0, l0);
    MFMAS(a1, l1, b1, m1);           // tile it
    LGKM0(); SBAR();
    if (it + 3 < nk) stage((it + 3) * BK, 0);
  }
  // tail: it == nk-1 (odd); in flight: stage(nk-1)·4 then B(nk-2)·8
  WAITV8(); SBAR();                  // stage(nk-1) done
  LOADB(b1, m1, nk - 1);
  READFA(1, a1, l1);
  MFMAS(a0, l0, b0, m0);             // tile nk-2
  LGKM0();
  MFMAS(a1, l1, b1, m1);             // tile nk-1 (compiler waits B(nk-1))

  // ---- epilogue: undo 256x W-scale, leaky relu, write next state / output
  const float inv = 1.0f / 256.0f;
#pragma unroll
  for (int i = 0; i < 4; i++) {
#pragma unroll
    for (int j = 0; j < 4; j++) {
#pragma unroll
      for (int e = 0; e < 4; e++) {
        int r = bm + wm * 64 + i * 16 + fq * 4 + e;  // C/D: row=(lane>>4)*4+reg
        int c = bn + wn * 64 + j * 16 + fm;          //      col=lane&15
        float g = acc[i][j][e] * inv;
        float s = (g > 0.0f) ? g : 0.1f * g;
        if (MODE == 0) {
          _Float16 h = (_Float16)s;
          Dh[(size_t)r * NDIM + c] = h;
          Dl[(size_t)r * NDIM + c] = (_Float16)(s - (float)h);
        } else {
          Dout[(size_t)r * NDIM + c] = s;
        }
      }
    }
  }
}

extern "C" void kernel_launch(void* const* d_in, const int* in_sizes, int n_in,
                              void* d_out, int out_size, void* d_ws, size_t ws_size,
                              hipStream_t stream) {
  const float* x = (const float*)d_in[0];  // [2048, 512]
  const float* W = (const float*)d_in[1];  // [4096, 4096]
  float* out = (float*)d_out;              // [2048, 4096]
  char* ws = (char*)d_ws;

  const size_t WT_BYTES = (size_t)NDIM * NDIM * 2;  // 32 MB each
  const size_t S_BYTES = (size_t)BATCH * NDIM * 2;  // 16 MB each
  _Float16* Wth = (_Float16*)ws;
  _Float16* Wtl = (_Float16*)(ws + WT_BYTES);
  _Float16* SAh = (_Float16*)(ws + 2 * WT_BYTES);
  _Float16* SAl = (_Float16*)(ws + 2 * WT_BYTES + S_BYTES);
  _Float16* SBh = (_Float16*)(ws + 2 * WT_BYTES + 2 * S_BYTES);
  _Float16* SBl = (_Float16*)(ws + 2 * WT_BYTES + 3 * S_BYTES);

  prep_x<<<(BATCH * NDIM) / 256, 256, 0, stream>>>(x, SAh, SAl);
  prep_w<<<dim3(NDIM / 32, NDIM / 32), dim3(32, 8), 0, stream>>>(W, Wth, Wtl);

  dim3 grid((NDIM / BN) * (BATCH / BM));  // 512 linear, swizzled in-kernel
  for (int t = 1; t <= 16; t++) {
    const _Float16* ah = (t & 1) ? SAh : SBh;
    const _Float16* al = (t & 1) ? SAl : SBl;
    _Float16* dh = (t & 1) ? SBh : SAh;
    _Float16* dl = (t & 1) ? SBl : SAl;
    int klen = (t == 1) ? INDIM : NDIM;
    if (t < 16)
      step_kernel<0><<<grid, 256, 0, stream>>>(ah, al, Wth, Wtl, dh, dl, nullptr, klen);
    else
      step_kernel<1><<<grid, 256, 0, stream>>>(ah, al, Wth, Wtl, nullptr, nullptr, out, klen);
  }
}